// Round 11
// baseline (291.665 us; speedup 1.0000x reference)
//
#include <hip/hip_runtime.h>

// SSIM loss, separable 11-tap Gaussian. R11 = R10 compute (unchanged) +
// reduction folded into main. Cross-round evidence: variants with a dependent
// kernel AFTER main show total-main gap 82-96us; R4 (folded, init-before)
// showed 29us. Fold via HIERARCHICAL tickets to avoid R5/R6's single-line
// atomic serialization: 48 per-slice ticket lines (<=128 arrivals each) ->
// slice reducer -> 1 master line (48 arrivals) -> final writer.

typedef _Float16 h2 __attribute__((ext_vector_type(2)));
typedef __fp16 fp16x2 __attribute__((ext_vector_type(2)));

__device__ __forceinline__ unsigned h2u(h2 v) { return __builtin_bit_cast(unsigned, v); }
__device__ __forceinline__ unsigned h2u(fp16x2 v) { return __builtin_bit_cast(unsigned, v); }
__device__ __forceinline__ h2 u2h(unsigned u) { return __builtin_bit_cast(h2, u); }
__device__ __forceinline__ h2 pkfma(h2 a, h2 b, h2 c) {
    return __builtin_elementwise_fma(a, b, c);
}
__device__ __forceinline__ unsigned pk2(float a, float b) {
    return h2u(__builtin_amdgcn_cvt_pkrtz(a, b));
}
__device__ __forceinline__ float fdot2_(h2 a, h2 b, float c) {
#if defined(__has_builtin) && __has_builtin(__builtin_amdgcn_fdot2)
    return __builtin_amdgcn_fdot2(a, b, c, false);
#else
    return fmaf((float)a[1], (float)b[1], fmaf((float)a[0], (float)b[0], c));
#endif
}

#define SXW 44   // staged row-pair stride in words (42 cols + pad, mult of 4)
#define HPW 36   // h row-pair stride in words (32 cols + pad, mult of 4)

__global__ void ssim_init(unsigned* tick) {
    if (threadIdx.x < 49) tick[threadIdx.x] = 0u;   // 48 slice + 1 master
}

__global__ __launch_bounds__(256, 4) void ssim_main(
    const float* __restrict__ xg, const float* __restrict__ yg,
    const float* __restrict__ w2d, float* __restrict__ part,
    float* __restrict__ slice, unsigned* __restrict__ tick,
    float* __restrict__ out, float invN)
{
    __shared__ __align__(16) unsigned sxrp[37 * SXW];   // 6.5 KB x row-pairs
    __shared__ __align__(16) unsigned syrp[37 * SXW];   // 6.5 KB y row-pairs
    __shared__ __align__(16) unsigned hq[5][37 * HPW];  // 26.6 KB h row-pairs
    __shared__ float gsf[11];
    __shared__ float wred[4];
    __shared__ int flag1, flag2;

    const int tid = threadIdx.x;

    if (tid < 11) {
        float s = 0.0f;
        #pragma unroll
        for (int j = 0; j < 11; ++j) s += w2d[tid * 11 + j];
        gsf[tid] = s;
    }

    // Tile: 32 cols x 64 rows. Staged: 42 cols x 74 rows (37 row-pairs).
    const int x0 = blockIdx.x * 32 - 5;
    const int y0 = blockIdx.y * 64 - 5;
    const size_t zoff = (size_t)blockIdx.z * (512 * 512);
    const float* __restrict__ xp = xg + zoff;
    const float* __restrict__ yp = yg + zoff;

    // Phase A: stage 37 row-pairs x 42 cols, zero-padded, row-pair packed.
    const bool interior = (x0 >= 0) & (x0 + 41 < 512) & (y0 >= 0) & (y0 + 73 < 512);
    if (interior) {
        for (int it = tid; it < 37 * 42; it += 256) {
            const int rp = it / 42, c = it - rp * 42;
            const int o = (y0 + 2 * rp) * 512 + x0 + c;
            sxrp[rp * SXW + c] = pk2(xp[o], xp[o + 512]);
            syrp[rp * SXW + c] = pk2(yp[o], yp[o + 512]);
        }
    } else {
        for (int it = tid; it < 37 * 42; it += 256) {
            const int rp = it / 42, c = it - rp * 42;
            const int gc = x0 + c;
            const int gr0 = y0 + 2 * rp;
            const bool cok = (unsigned)gc < 512u;
            float xv0 = 0.f, xv1 = 0.f, yv0 = 0.f, yv1 = 0.f;
            if (cok && (unsigned)gr0 < 512u) {
                const int o = gr0 * 512 + gc; xv0 = xp[o]; yv0 = yp[o];
            }
            if (cok && (unsigned)(gr0 + 1) < 512u) {
                const int o = (gr0 + 1) * 512 + gc; xv1 = xp[o]; yv1 = yp[o];
            }
            sxrp[rp * SXW + c] = pk2(xv0, xv1);
            syrp[rp * SXW + c] = pk2(yv0, yv1);
        }
    }
    __syncthreads();

    // Taps in f16 (center-corrected sum ~1).
    h2 g2[11], ge[6], go[6];
    {
        _Float16 gh[12]; float ssum = 0.0f;
        #pragma unroll
        for (int k = 0; k < 11; ++k) {
            gh[k] = (_Float16)gsf[k];
            if (k != 5) ssum += (float)gh[k];
        }
        gh[5] = (_Float16)(1.0f - ssum);
        gh[11] = (_Float16)0.0f;
        #pragma unroll
        for (int k = 0; k < 11; ++k) g2[k] = (h2){gh[k], gh[k]};
        #pragma unroll
        for (int t = 0; t < 6; ++t) {
            ge[t] = (h2){gh[2 * t], gh[2 * t + 1]};
            go[t] = (h2){(t == 0) ? (_Float16)0.f : gh[2 * t - 1], gh[2 * t]};
        }
    }

    // Phase B: horizontal conv on row-pairs.
    for (int it = tid; it < 37 * 8; it += 256) {
        const int rp = it >> 3, cq = it & 7;
        const int base = rp * SXW + 4 * cq;
        unsigned X[16], Y[16];
        *(uint4*)&X[0]  = *(const uint4*)&sxrp[base];
        *(uint4*)&X[4]  = *(const uint4*)&sxrp[base + 4];
        *(uint4*)&X[8]  = *(const uint4*)&sxrp[base + 8];
        *(uint4*)&X[12] = *(const uint4*)&sxrp[base + 12];
        *(uint4*)&Y[0]  = *(const uint4*)&syrp[base];
        *(uint4*)&Y[4]  = *(const uint4*)&syrp[base + 4];
        *(uint4*)&Y[8]  = *(const uint4*)&syrp[base + 8];
        *(uint4*)&Y[12] = *(const uint4*)&syrp[base + 12];

        const int ob = rp * HPW + 4 * cq;
        auto conv_store = [&](const unsigned* S, int qi) {
            h2 a0 = (h2)0, a1 = (h2)0, a2 = (h2)0, a3 = (h2)0;
            #pragma unroll
            for (int k = 0; k < 11; ++k) {
                const h2 gk = g2[k];
                a0 = pkfma(gk, u2h(S[k]),     a0);
                a1 = pkfma(gk, u2h(S[k + 1]), a1);
                a2 = pkfma(gk, u2h(S[k + 2]), a2);
                a3 = pkfma(gk, u2h(S[k + 3]), a3);
            }
            *(uint4*)&hq[qi][ob] = make_uint4(h2u(a0), h2u(a1), h2u(a2), h2u(a3));
        };

        conv_store(X, 0);
        conv_store(Y, 1);
        unsigned T[14];
        #pragma unroll
        for (int i = 0; i < 14; ++i) { const h2 v = u2h(X[i]); T[i] = h2u(v * v); }
        conv_store(T, 2);
        #pragma unroll
        for (int i = 0; i < 14; ++i) { const h2 v = u2h(Y[i]); T[i] = h2u(v * v); }
        conv_store(T, 3);
        #pragma unroll
        for (int i = 0; i < 14; ++i) { T[i] = h2u(u2h(X[i]) * u2h(Y[i])); }
        conv_store(T, 4);
    }
    __syncthreads();

    // Phase C: vertical conv + SSIM. Thread = (row-quad rq, col-pair cp).
    const int rq = tid >> 4, cp = tid & 15;
    float A_[5][4][2];
    #pragma unroll
    for (int q = 0; q < 5; ++q)
        #pragma unroll
        for (int e = 0; e < 4; ++e) { A_[q][e][0] = 0.f; A_[q][e][1] = 0.f; }

    #pragma unroll
    for (int q = 0; q < 5; ++q) {
        #pragma unroll
        for (int t = 0; t < 7; ++t) {
            const uint2 V = *(const uint2*)&hq[q][(2 * rq + t) * HPW + 2 * cp];
            const h2 p0 = u2h(V.x), p1 = u2h(V.y);
            if (t < 6) {
                A_[q][0][0] = fdot2_(ge[t], p0, A_[q][0][0]);
                A_[q][0][1] = fdot2_(ge[t], p1, A_[q][0][1]);
                A_[q][1][0] = fdot2_(go[t], p0, A_[q][1][0]);
                A_[q][1][1] = fdot2_(go[t], p1, A_[q][1][1]);
            }
            if (t >= 1) {
                A_[q][2][0] = fdot2_(ge[t - 1], p0, A_[q][2][0]);
                A_[q][2][1] = fdot2_(ge[t - 1], p1, A_[q][2][1]);
                A_[q][3][0] = fdot2_(go[t - 1], p0, A_[q][3][0]);
                A_[q][3][1] = fdot2_(go[t - 1], p1, A_[q][3][1]);
            }
        }
    }

    float lsum = 0.0f;
    const float C1 = 1e-4f, C2 = 9e-4f;
    #pragma unroll
    for (int e = 0; e < 4; ++e) {
        #pragma unroll
        for (int el = 0; el < 2; ++el) {
            const float mx  = A_[0][e][el], my  = A_[1][e][el];
            const float exx = A_[2][e][el], eyy = A_[3][e][el];
            const float exy = A_[4][e][el];
            const float mx2 = mx * mx, my2 = my * my, mxy = mx * my;
            const float vx = exx - mx2, vy = eyy - my2, vxy = exy - mxy;
            const float num = (2.0f * mxy + C1) * (2.0f * vxy + C2);
            const float den = (mx2 + my2 + C1) * (vx + vy + C2) + 1e-12f;
            lsum = fmaf(num, __builtin_amdgcn_rcpf(den), lsum);
        }
    }

    // Wave reduce -> cross-wave via LDS -> per-block partial.
    #pragma unroll
    for (int off = 32; off > 0; off >>= 1)
        lsum += __shfl_down(lsum, off, 64);
    if ((tid & 63) == 0) wred[tid >> 6] = lsum;
    __syncthreads();

    // Hierarchical completion: slice line (<=128 arrivals) -> master (48).
    const int z = blockIdx.z;
    const int lbid = blockIdx.y * gridDim.x + blockIdx.x;   // 0..127
    if (tid == 0) {
        part[z * 128 + lbid] = wred[0] + wred[1] + wred[2] + wred[3];
        __threadfence();
        const unsigned o = atomicAdd(&tick[z], 1u);
        flag1 = (o == 127u);
    }
    __syncthreads();
    if (flag1) {
        // This block is the last finisher of slice z: reduce its 128 partials.
        float s = 0.0f;
        if (tid < 128) s = atomicAdd(&part[z * 128 + tid], 0.0f);  // coherent
        #pragma unroll
        for (int off = 32; off > 0; off >>= 1)
            s += __shfl_down(s, off, 64);
        if ((tid & 63) == 0) wred[tid >> 6] = s;
        __syncthreads();
        if (tid == 0) {
            slice[z] = wred[0] + wred[1];
            __threadfence();
            const unsigned m = atomicAdd(&tick[48], 1u);
            flag2 = (m == 47u);
        }
        __syncthreads();
        if (flag2) {
            // Globally last: reduce 48 slice sums, write the scalar.
            float t = 0.0f;
            if (tid < 48) t = atomicAdd(&slice[tid], 0.0f);        // coherent
            #pragma unroll
            for (int off = 32; off > 0; off >>= 1)
                t += __shfl_down(t, off, 64);
            if (tid == 0) out[0] = 1.0f - t * invN;
        }
    }
}

extern "C" void kernel_launch(void* const* d_in, const int* in_sizes, int n_in,
                              void* d_out, int out_size, void* d_ws, size_t ws_size,
                              hipStream_t stream) {
    const float* x   = (const float*)d_in[0];
    const float* y   = (const float*)d_in[1];
    const float* w2d = (const float*)d_in[2];  // (3,1,11,11); channels identical
    float* out   = (float*)d_out;
    float* part  = (float*)d_ws;               // 6144 floats
    float* slice = part + 6144;                // 48 floats
    unsigned* tick = (unsigned*)(slice + 48);  // 48 slice + 1 master

    const int H = 512, W = 512;
    const int total = in_sizes[0];              // 16*3*512*512
    const int Z = total / (H * W);              // 48

    ssim_init<<<1, 64, 0, stream>>>(tick);

    dim3 grid(W / 32, H / 64, Z);               // 16 x 8 x 48 = 6144 blocks
    const float invN = 1.0f / (float)total;
    ssim_main<<<grid, 256, 0, stream>>>(x, y, w2d, part, slice, tick, out, invN);
}